// Round 12
// baseline (123.617 us; speedup 1.0000x reference)
//
#include <hip/hip_runtime.h>

typedef float f32x4 __attribute__((ext_vector_type(4)));
typedef __bf16 bf16x8 __attribute__((ext_vector_type(8)));
typedef unsigned short u16;

__device__ __forceinline__ f32x4 mfma16(bf16x8 a, bf16x8 b, f32x4 c) {
  return __builtin_amdgcn_mfma_f32_16x16x32_bf16(a, b, c, 0, 0, 0);
}

// Fragment-linear pack: matrix [R][1024] row-major, 32 k-tiles of 32.
// 16B chunk (row, kc), kc = k/8 in 0..127:
//   off16 = (((row>>6)*32 + (kc>>2))*4 + ((row>>4)&3))*64 + (kc&3)*16 + (row&15)
// => fragment (mi, kt, mt) is a contiguous 1 KB; lane l holds
//    row = mi*64+mt*16+(l&15), k = kt*32+(l>>4)*8..+7  (MFMA A/B layout).
__device__ __forceinline__ int pidx16(int row, int kc) {
  return ((((row >> 6) * 32 + (kc >> 2)) * 4 + ((row >> 4) & 3)) << 6) +
         ((kc & 3) << 4) + (row & 15);
}

// ---------------- fused f32->bf16 convert + fragment-linear pack ----------
__global__ void cvt3_kernel(const float* __restrict__ x,
                            const float* __restrict__ wp,
                            const float* __restrict__ wo,
                            u16* __restrict__ apx, u16* __restrict__ bpx,
                            u16* __restrict__ wox) {
  int idx = blockIdx.x * blockDim.x + threadIdx.x;
  int stride = gridDim.x * blockDim.x;
  for (int i = idx; i < 1048576; i += stride) {
    const float* src;
    u16* dst;
    int j;
    if (i < 524288) {
      j = i; src = x + (size_t)j * 8; dst = apx;
    } else if (i < 917504) {
      j = i - 524288; src = wp + (size_t)j * 8; dst = bpx;
    } else {
      j = i - 917504; src = wo + (size_t)j * 8; dst = wox;
    }
    f32x4 a = *(const f32x4*)src;
    f32x4 b = *(const f32x4*)(src + 4);
    bf16x8 r;
#pragma unroll
    for (int e = 0; e < 4; ++e) {
      r[e] = (__bf16)a[e];
      r[4 + e] = (__bf16)b[e];
    }
    int row = j >> 7, kc = j & 127;
    *(bf16x8*)(dst + (size_t)pidx16(row, kc) * 8) = r;
  }
}

// ---------------- barrier-free fragment GEMM: C = A @ B^T + bias ----------
// 1-wave blocks, wave owns 64x64 output tile. A/B pre-packed fragment-linear
// (each fragment load = contiguous 1 KB from L2). Double-buffered register
// prefetch; no LDS, no barriers -> latency hidden by TLP + pipelining.
// MODE 0: f32 out. MODE 1: QKV pack (Q row-major; K/V fragment tiles).
template <int MODE>
__global__ __launch_bounds__(64, 3) void gemm_frag(
    const u16* __restrict__ apx, const u16* __restrict__ bpx,
    const float* __restrict__ bias, float* __restrict__ Cout,
    __bf16* __restrict__ qb, __bf16* __restrict__ kp, __bf16* __restrict__ vp,
    int N, int ntiles) {
  const int lane = threadIdx.x & 63;
  const int lr = lane & 15, lg = lane >> 4;
  // bijective XCD swizzle (gridDim.x % 8 == 0)
  const int nwg = gridDim.x;
  const int lid = blockIdx.x;
  const int sw = (lid & 7) * (nwg >> 3) + (lid >> 3);
  const int ni = sw % ntiles, mi = sw / ntiles;

  const u16* ab = apx + (size_t)mi * 65536 + lane * 8;  // + kt*2048 + mt*512
  const u16* bb = bpx + (size_t)ni * 65536 + lane * 8;

  f32x4 acc[4][4] = {};
  bf16x8 a0[4], b0[4], a1[4], b1[4];
#pragma unroll
  for (int mt = 0; mt < 4; ++mt) {
    a0[mt] = *(const bf16x8*)(ab + mt * 512);
    b0[mt] = *(const bf16x8*)(bb + mt * 512);
  }
  for (int kt = 0; kt < 32; kt += 2) {
#pragma unroll
    for (int mt = 0; mt < 4; ++mt) {
      a1[mt] = *(const bf16x8*)(ab + (kt + 1) * 2048 + mt * 512);
      b1[mt] = *(const bf16x8*)(bb + (kt + 1) * 2048 + mt * 512);
    }
#pragma unroll
    for (int mt = 0; mt < 4; ++mt)
#pragma unroll
      for (int nt = 0; nt < 4; ++nt)
        acc[mt][nt] = mfma16(a0[mt], b0[nt], acc[mt][nt]);
    if (kt + 2 < 32) {
#pragma unroll
      for (int mt = 0; mt < 4; ++mt) {
        a0[mt] = *(const bf16x8*)(ab + (kt + 2) * 2048 + mt * 512);
        b0[mt] = *(const bf16x8*)(bb + (kt + 2) * 2048 + mt * 512);
      }
    }
#pragma unroll
    for (int mt = 0; mt < 4; ++mt)
#pragma unroll
      for (int nt = 0; nt < 4; ++nt)
        acc[mt][nt] = mfma16(a1[mt], b1[nt], acc[mt][nt]);
  }

  // epilogue: C/D layout col = lane&15, row = (lane>>4)*4 + r
#pragma unroll
  for (int nt = 0; nt < 4; ++nt) {
    int col = ni * 64 + nt * 16 + lr;
    float bv = bias[col];
#pragma unroll
    for (int mt = 0; mt < 4; ++mt) {
#pragma unroll
      for (int r = 0; r < 4; ++r) {
        int row = mi * 64 + mt * 16 + lg * 4 + r;
        float val = acc[mt][nt][r] + bv;
        if (MODE == 0) {
          Cout[(size_t)row * N + col] = val;
        } else {
          __bf16 bx = (__bf16)val;
          int b = row >> 11, s = row & 2047;
          int third = col >> 10, hd = col & 1023;
          int h = hd >> 6, d = hd & 63;
          if (third == 0) {
            qb[(size_t)row * 1024 + hd] = bx;
          } else {
            int bh = b * 16 + h, t2 = s >> 6, sr = s & 63;
            size_t tb = ((size_t)(bh * 32 + t2)) * 4096;
            if (third == 1)
              kp[tb + (sr >> 4) * 1024 + (d >> 5) * 512 + ((d >> 3) & 3) * 128 +
                 (sr & 15) * 8 + (d & 7)] = bx;
            else
              vp[tb + (d >> 4) * 1024 + (sr >> 5) * 512 + ((sr >> 3) & 3) * 128 +
                 (d & 15) * 8 + (sr & 7)] = bx;
          }
        }
      }
    }
  }
}

// ---------------- fused causal+ALiBi flash attention ----------------
// 4096 independent 1-wave blocks; K/V fragment-linear packed tiles in L2.
// Output written FRAGMENT-PACKED (A-operand layout for gemm2).
__global__ __launch_bounds__(64, 4) void attn_kernel(
    const __bf16* __restrict__ qb, const __bf16* __restrict__ kp,
    const __bf16* __restrict__ vp, u16* __restrict__ abp) {
  __shared__ __bf16 p_lds[16][72];
  const int lane = threadIdx.x & 63;
  const int lr = lane & 15;
  const int lg = lane >> 4;

  const int lid = blockIdx.x;
  const int xcd = lid & 7;
  const int rest = lid >> 3;
  const int bh = xcd * 4 + (rest & 3);
  const int a16 = 127 - (rest >> 2);
  const int b = bh >> 4, h = bh & 15;
  const int qr0 = a16 * 16;
  const int ntl = (a16 >> 2) + 1;

  const float LOG2E = 1.4426950408889634f;
  const float c1 = 0.125f * LOG2E;
  const float c2 = exp2f(-(float)(h + 1) * 0.5f) * LOG2E;

  bf16x8 ones;
#pragma unroll
  for (int j = 0; j < 8; ++j) ones[j] = (__bf16)1.0f;

  const u16* ktiles = (const u16*)kp + (size_t)bh * 32 * 4096;
  const u16* vtiles = (const u16*)vp + (size_t)bh * 32 * 4096;

  const __bf16* qrow = qb + (size_t)(b * 2048 + qr0 + lr) * 1024 + h * 64;
  bf16x8 qf0 = *(const bf16x8*)(qrow + lg * 8);
  bf16x8 qf1 = *(const bf16x8*)(qrow + 32 + lg * 8);

  float m[4], l[4], cq[4];
  f32x4 o[4];
#pragma unroll
  for (int r = 0; r < 4; ++r) {
    m[r] = 0.f;
    l[r] = 0.f;
    cq[r] = c2 * (float)(qr0 + lg * 4 + r);
  }
#pragma unroll
  for (int dt = 0; dt < 4; ++dt) o[dt] = (f32x4){0.f, 0.f, 0.f, 0.f};

  for (int t = 0; t < ntl; ++t) {
    const u16* kb = ktiles + (size_t)t * 4096;
    const u16* vb = vtiles + (size_t)t * 4096;
    const int kv = t * 64;
    const bool last = (t == ntl - 1);

    bf16x8 ka[8], va[8];
#pragma unroll
    for (int j = 0; j < 8; ++j)
      ka[j] = *(const bf16x8*)(kb + j * 512 + lane * 8);
#pragma unroll
    for (int j = 0; j < 8; ++j)
      va[j] = *(const bf16x8*)(vb + j * 512 + lane * 8);

    f32x4 s[4];
#pragma unroll
    for (int nt = 0; nt < 4; ++nt) {
      f32x4 tt = (f32x4){0.f, 0.f, 0.f, 0.f};
      tt = mfma16(qf0, ka[nt * 2], tt);
      tt = mfma16(qf1, ka[nt * 2 + 1], tt);
      s[nt] = tt;
    }

#pragma unroll
    for (int nt = 0; nt < 4; ++nt) {
      float bnt = c2 * (float)(kv + nt * 16 + lr);
#pragma unroll
      for (int r = 0; r < 4; ++r)
        s[nt][r] = __builtin_fmaf(s[nt][r], c1, bnt - cq[r]);
    }
    if (last) {
#pragma unroll
      for (int nt = 0; nt < 4; ++nt) {
        float kf = (float)(kv + nt * 16 + lr);
#pragma unroll
        for (int r = 0; r < 4; ++r) {
          float qi = (float)(qr0 + lg * 4 + r);
          if (kf > qi) s[nt][r] = -1e30f;
        }
      }
    }

    float pm[4];
#pragma unroll
    for (int r = 0; r < 4; ++r)
      pm[r] = fmaxf(fmaxf(s[0][r], s[1][r]), fmaxf(s[2][r], s[3][r]));
    bool ok = (pm[0] <= m[0] + 8.f) && (pm[1] <= m[1] + 8.f) &&
              (pm[2] <= m[2] + 8.f) && (pm[3] <= m[3] + 8.f);
    if (!__all(ok)) {
#pragma unroll
      for (int r = 0; r < 4; ++r)
#pragma unroll
        for (int d = 1; d < 16; d <<= 1)
          pm[r] = fmaxf(pm[r], __shfl_xor(pm[r], d));
#pragma unroll
      for (int r = 0; r < 4; ++r) {
        float mn = fmaxf(m[r], pm[r]);
        float fac = __builtin_amdgcn_exp2f(m[r] - mn);
        m[r] = mn;
        l[r] *= fac;
#pragma unroll
        for (int dt = 0; dt < 4; ++dt) o[dt][r] *= fac;
      }
    }

#pragma unroll
    for (int nt = 0; nt < 4; ++nt)
#pragma unroll
      for (int r = 0; r < 4; ++r) {
        float e = __builtin_amdgcn_exp2f(s[nt][r] - m[r]);
        p_lds[lg * 4 + r][nt * 16 + lr] = (__bf16)e;
      }

    bf16x8 pa0 = *(const bf16x8*)&p_lds[lr][lg * 8];
    bf16x8 pa1 = *(const bf16x8*)&p_lds[lr][32 + lg * 8];

    {
      f32x4 tt = (f32x4){0.f, 0.f, 0.f, 0.f};
      tt = mfma16(pa0, ones, tt);
      tt = mfma16(pa1, ones, tt);
#pragma unroll
      for (int r = 0; r < 4; ++r) l[r] += tt[r];
    }

#pragma unroll
    for (int dt = 0; dt < 4; ++dt) {
      o[dt] = mfma16(pa0, va[dt * 2], o[dt]);
      o[dt] = mfma16(pa1, va[dt * 2 + 1], o[dt]);
    }
  }

  // ---- epilogue: write output fragment-packed (gemm2 A-operand) ----
  // element (row = b*2048 + qr0 + lg*4 + r, k = h*64 + dt*16 + lr):
  //   mi = b*32 + (a16>>2), kt = h*2 + (dt>>1), mt = a16&3,
  //   lane' = ((dt&1)*2 + (lr>>3))*16 + lg*4 + r, e = lr&7
  const int mi_g = b * 32 + (a16 >> 2);
#pragma unroll
  for (int dt = 0; dt < 4; ++dt)
#pragma unroll
    for (int r = 0; r < 4; ++r) {
      float val = o[dt][r] / l[r];
      __bf16 bx = (__bf16)val;
      int off16 = (((mi_g * 32 + h * 2 + (dt >> 1)) * 4 + (a16 & 3)) << 6) +
                  (((dt & 1) * 2 + (lr >> 3)) << 4) + lg * 4 + r;
      abp[(size_t)off16 * 8 + (lr & 7)] = *(u16*)&bx;
    }
}

extern "C" void kernel_launch(void* const* d_in, const int* in_sizes, int n_in,
                              void* d_out, int out_size, void* d_ws, size_t ws_size,
                              hipStream_t stream) {
  (void)in_sizes; (void)n_in; (void)out_size; (void)ws_size;
  const float* x = (const float*)d_in[0];
  const float* Wp = (const float*)d_in[1];
  const float* bp = (const float*)d_in[2];
  const float* Wo = (const float*)d_in[3];
  const float* bo = (const float*)d_in[4];
  float* out = (float*)d_out;

  char* ws = (char*)d_ws;
  u16* apx = (u16*)(ws);                        // 8 MB  x packed [64 mi]
  u16* bpx = (u16*)(ws + (size_t)(8u << 20));   // 6 MB  Wp packed [48 ni]
  u16* wox = (u16*)(ws + (size_t)(14u << 20));  // 2 MB  Wo packed [16 ni]
  u16* qbp = (u16*)(ws + (size_t)(16u << 20));  // 8 MB  Q row-major
  u16* kpp = (u16*)(ws + (size_t)(24u << 20));  // 8 MB  K fragment tiles
  u16* vpp = (u16*)(ws + (size_t)(32u << 20));  // 8 MB  V fragment tiles
  u16* abp = (u16*)(ws + (size_t)(40u << 20));  // 8 MB  attn out packed

  cvt3_kernel<<<2048, 256, 0, stream>>>(x, Wp, Wo, apx, bpx, wox);
  // gemm1: 64 mi x 48 ni = 3072 one-wave blocks
  gemm_frag<1><<<3072, 64, 0, stream>>>(
      apx, bpx, bp, nullptr, (__bf16*)qbp, (__bf16*)kpp, (__bf16*)vpp,
      3072, 48);
  attn_kernel<<<4096, 64, 0, stream>>>(
      (const __bf16*)qbp, (const __bf16*)kpp, (const __bf16*)vpp, abp);
  // gemm2: 64 mi x 16 ni = 1024 one-wave blocks
  gemm_frag<0><<<1024, 64, 0, stream>>>(
      abp, wox, bo, out, nullptr, nullptr, nullptr, 1024, 16);
}

// Round 13
// 119.607 us; speedup vs baseline: 1.0335x; 1.0335x over previous
//
#include <hip/hip_runtime.h>

typedef float f32x4 __attribute__((ext_vector_type(4)));
typedef __bf16 bf16x8 __attribute__((ext_vector_type(8)));
typedef unsigned short u16;

__device__ __forceinline__ f32x4 mfma16(bf16x8 a, bf16x8 b, f32x4 c) {
  return __builtin_amdgcn_mfma_f32_16x16x32_bf16(a, b, c, 0, 0, 0);
}

// Fragment-linear pack: matrix [R][1024] row-major, 32 k-tiles of 32.
// 16B chunk (row, kc), kc = k/8 in 0..127:
//   off16 = (((row>>6)*32 + (kc>>2))*4 + ((row>>4)&3))*64 + (kc&3)*16 + (row&15)
// => fragment (mi, kt, mt) is a contiguous 1 KB; lane l holds
//    row = mi*64+mt*16+(l&15), k = kt*32+(l>>4)*8..+7  (MFMA A/B layout).
__device__ __forceinline__ int pidx16(int row, int kc) {
  return ((((row >> 6) * 32 + (kc >> 2)) * 4 + ((row >> 4) & 3)) << 6) +
         ((kc & 3) << 4) + (row & 15);
}

// ---------------- fused f32->bf16 convert + fragment-linear pack ----------
__global__ void cvt3_kernel(const float* __restrict__ x,
                            const float* __restrict__ wp,
                            const float* __restrict__ wo,
                            u16* __restrict__ apx, u16* __restrict__ bpx,
                            u16* __restrict__ wox) {
  int idx = blockIdx.x * blockDim.x + threadIdx.x;
  int stride = gridDim.x * blockDim.x;
  for (int i = idx; i < 1048576; i += stride) {
    const float* src;
    u16* dst;
    int j;
    if (i < 524288) {
      j = i; src = x + (size_t)j * 8; dst = apx;
    } else if (i < 917504) {
      j = i - 524288; src = wp + (size_t)j * 8; dst = bpx;
    } else {
      j = i - 917504; src = wo + (size_t)j * 8; dst = wox;
    }
    f32x4 a = *(const f32x4*)src;
    f32x4 b = *(const f32x4*)(src + 4);
    bf16x8 r;
#pragma unroll
    for (int e = 0; e < 4; ++e) {
      r[e] = (__bf16)a[e];
      r[4 + e] = (__bf16)b[e];
    }
    int row = j >> 7, kc = j & 127;
    *(bf16x8*)(dst + (size_t)pidx16(row, kc) * 8) = r;
  }
}

// ---------------- barrier-free fragment GEMM: C = A @ B^T + bias ----------
// 4-wave blocks stacked in M (block tile 256 x NREP*16); waves independent
// (no barriers, no LDS) and SHARE the B tile -> L1 reuse x4.
// XCD-local mapping: xcd owns mi-blocks {xcd*2, xcd*2+1} (A chunk = 1 MB,
// L2-resident) and walks nj in order (B streams through L2).
// A/B pre-packed fragment-linear: every fragment load = contiguous 1 KB.
// NREP: 4 = 64-col wave tile (gemm1), 2 = 32-col (gemm2, 2 waves/SIMD).
// MODE 0: f32 out. MODE 1: QKV pack (Q row-major; K/V fragment tiles).
template <int NREP, int MODE>
__global__ __launch_bounds__(256, 2) void gemm_frag(
    const u16* __restrict__ apx, const u16* __restrict__ bpx,
    const float* __restrict__ bias, float* __restrict__ Cout,
    __bf16* __restrict__ qb, __bf16* __restrict__ kp, __bf16* __restrict__ vp,
    int N) {
  const int tid = threadIdx.x;
  const int wid = tid >> 6;
  const int lane = tid & 63;
  const int lr = lane & 15, lg = lane >> 4;

  const int lid = blockIdx.x;
  const int xcd = lid & 7;
  const int local = lid >> 3;
  const int mib = xcd * 2 + (local & 1);  // 256-row block, XCD-resident
  const int nj = local >> 1;              // col tile (NREP*16 wide), in order
  const int mi64 = mib * 4 + wid;

  const u16* ab = apx + (size_t)mi64 * 65536 + lane * 8;
  const u16* bb;
  int colbase;
  if (NREP == 4) {
    bb = bpx + (size_t)nj * 65536 + lane * 8;
    colbase = nj * 64;
  } else {
    bb = bpx + (size_t)(nj >> 1) * 65536 + (nj & 1) * 1024 + lane * 8;
    colbase = nj * 32;
  }

  f32x4 acc[4][NREP] = {};
  bf16x8 a0[4], b0[NREP], a1[4], b1[NREP];
#pragma unroll
  for (int mt = 0; mt < 4; ++mt) a0[mt] = *(const bf16x8*)(ab + mt * 512);
#pragma unroll
  for (int nt = 0; nt < NREP; ++nt) b0[nt] = *(const bf16x8*)(bb + nt * 512);

  for (int kt = 0; kt < 32; kt += 2) {
#pragma unroll
    for (int mt = 0; mt < 4; ++mt)
      a1[mt] = *(const bf16x8*)(ab + (kt + 1) * 2048 + mt * 512);
#pragma unroll
    for (int nt = 0; nt < NREP; ++nt)
      b1[nt] = *(const bf16x8*)(bb + (kt + 1) * 2048 + nt * 512);
#pragma unroll
    for (int mt = 0; mt < 4; ++mt)
#pragma unroll
      for (int nt = 0; nt < NREP; ++nt)
        acc[mt][nt] = mfma16(a0[mt], b0[nt], acc[mt][nt]);
    if (kt + 2 < 32) {
#pragma unroll
      for (int mt = 0; mt < 4; ++mt)
        a0[mt] = *(const bf16x8*)(ab + (kt + 2) * 2048 + mt * 512);
#pragma unroll
      for (int nt = 0; nt < NREP; ++nt)
        b0[nt] = *(const bf16x8*)(bb + (kt + 2) * 2048 + nt * 512);
    }
#pragma unroll
    for (int mt = 0; mt < 4; ++mt)
#pragma unroll
      for (int nt = 0; nt < NREP; ++nt)
        acc[mt][nt] = mfma16(a1[mt], b1[nt], acc[mt][nt]);
  }

  // epilogue: C/D layout col = lane&15, row = (lane>>4)*4 + r
#pragma unroll
  for (int nt = 0; nt < NREP; ++nt) {
    int col = colbase + nt * 16 + lr;
    float bv = bias[col];
#pragma unroll
    for (int mt = 0; mt < 4; ++mt) {
#pragma unroll
      for (int r = 0; r < 4; ++r) {
        int row = mi64 * 64 + mt * 16 + lg * 4 + r;
        float val = acc[mt][nt][r] + bv;
        if (MODE == 0) {
          Cout[(size_t)row * N + col] = val;
        } else {
          __bf16 bx = (__bf16)val;
          int b = row >> 11, s = row & 2047;
          int third = col >> 10, hd = col & 1023;
          int h = hd >> 6, d = hd & 63;
          if (third == 0) {
            qb[(size_t)row * 1024 + hd] = bx;
          } else {
            int bh = b * 16 + h, t2 = s >> 6, sr = s & 63;
            size_t tb = ((size_t)(bh * 32 + t2)) * 4096;
            if (third == 1)
              kp[tb + (sr >> 4) * 1024 + (d >> 5) * 512 + ((d >> 3) & 3) * 128 +
                 (sr & 15) * 8 + (d & 7)] = bx;
            else
              vp[tb + (d >> 4) * 1024 + (sr >> 5) * 512 + ((sr >> 3) & 3) * 128 +
                 (d & 15) * 8 + (sr & 7)] = bx;
          }
        }
      }
    }
  }
}

// ---------------- fused causal+ALiBi flash attention ----------------
// 4096 independent 1-wave blocks; K/V fragment-linear packed tiles in L2.
// Output written FRAGMENT-PACKED (A-operand layout for gemm2).
__global__ __launch_bounds__(64, 4) void attn_kernel(
    const __bf16* __restrict__ qb, const __bf16* __restrict__ kp,
    const __bf16* __restrict__ vp, u16* __restrict__ abp) {
  __shared__ __bf16 p_lds[16][72];
  const int lane = threadIdx.x & 63;
  const int lr = lane & 15;
  const int lg = lane >> 4;

  const int lid = blockIdx.x;
  const int xcd = lid & 7;
  const int rest = lid >> 3;
  const int bh = xcd * 4 + (rest & 3);
  const int a16 = 127 - (rest >> 2);
  const int b = bh >> 4, h = bh & 15;
  const int qr0 = a16 * 16;
  const int ntl = (a16 >> 2) + 1;

  const float LOG2E = 1.4426950408889634f;
  const float c1 = 0.125f * LOG2E;
  const float c2 = exp2f(-(float)(h + 1) * 0.5f) * LOG2E;

  bf16x8 ones;
#pragma unroll
  for (int j = 0; j < 8; ++j) ones[j] = (__bf16)1.0f;

  const u16* ktiles = (const u16*)kp + (size_t)bh * 32 * 4096;
  const u16* vtiles = (const u16*)vp + (size_t)bh * 32 * 4096;

  const __bf16* qrow = qb + (size_t)(b * 2048 + qr0 + lr) * 1024 + h * 64;
  bf16x8 qf0 = *(const bf16x8*)(qrow + lg * 8);
  bf16x8 qf1 = *(const bf16x8*)(qrow + 32 + lg * 8);

  float m[4], l[4], cq[4];
  f32x4 o[4];
#pragma unroll
  for (int r = 0; r < 4; ++r) {
    m[r] = 0.f;
    l[r] = 0.f;
    cq[r] = c2 * (float)(qr0 + lg * 4 + r);
  }
#pragma unroll
  for (int dt = 0; dt < 4; ++dt) o[dt] = (f32x4){0.f, 0.f, 0.f, 0.f};

  for (int t = 0; t < ntl; ++t) {
    const u16* kb = ktiles + (size_t)t * 4096;
    const u16* vb = vtiles + (size_t)t * 4096;
    const int kv = t * 64;
    const bool last = (t == ntl - 1);

    bf16x8 ka[8], va[8];
#pragma unroll
    for (int j = 0; j < 8; ++j)
      ka[j] = *(const bf16x8*)(kb + j * 512 + lane * 8);
#pragma unroll
    for (int j = 0; j < 8; ++j)
      va[j] = *(const bf16x8*)(vb + j * 512 + lane * 8);

    f32x4 s[4];
#pragma unroll
    for (int nt = 0; nt < 4; ++nt) {
      f32x4 tt = (f32x4){0.f, 0.f, 0.f, 0.f};
      tt = mfma16(qf0, ka[nt * 2], tt);
      tt = mfma16(qf1, ka[nt * 2 + 1], tt);
      s[nt] = tt;
    }

#pragma unroll
    for (int nt = 0; nt < 4; ++nt) {
      float bnt = c2 * (float)(kv + nt * 16 + lr);
#pragma unroll
      for (int r = 0; r < 4; ++r)
        s[nt][r] = __builtin_fmaf(s[nt][r], c1, bnt - cq[r]);
    }
    if (last) {
#pragma unroll
      for (int nt = 0; nt < 4; ++nt) {
        float kf = (float)(kv + nt * 16 + lr);
#pragma unroll
        for (int r = 0; r < 4; ++r) {
          float qi = (float)(qr0 + lg * 4 + r);
          if (kf > qi) s[nt][r] = -1e30f;
        }
      }
    }

    float pm[4];
#pragma unroll
    for (int r = 0; r < 4; ++r)
      pm[r] = fmaxf(fmaxf(s[0][r], s[1][r]), fmaxf(s[2][r], s[3][r]));
    bool ok = (pm[0] <= m[0] + 8.f) && (pm[1] <= m[1] + 8.f) &&
              (pm[2] <= m[2] + 8.f) && (pm[3] <= m[3] + 8.f);
    if (!__all(ok)) {
#pragma unroll
      for (int r = 0; r < 4; ++r)
#pragma unroll
        for (int d = 1; d < 16; d <<= 1)
          pm[r] = fmaxf(pm[r], __shfl_xor(pm[r], d));
#pragma unroll
      for (int r = 0; r < 4; ++r) {
        float mn = fmaxf(m[r], pm[r]);
        float fac = __builtin_amdgcn_exp2f(m[r] - mn);
        m[r] = mn;
        l[r] *= fac;
#pragma unroll
        for (int dt = 0; dt < 4; ++dt) o[dt][r] *= fac;
      }
    }

#pragma unroll
    for (int nt = 0; nt < 4; ++nt)
#pragma unroll
      for (int r = 0; r < 4; ++r) {
        float e = __builtin_amdgcn_exp2f(s[nt][r] - m[r]);
        p_lds[lg * 4 + r][nt * 16 + lr] = (__bf16)e;
      }

    bf16x8 pa0 = *(const bf16x8*)&p_lds[lr][lg * 8];
    bf16x8 pa1 = *(const bf16x8*)&p_lds[lr][32 + lg * 8];

    {
      f32x4 tt = (f32x4){0.f, 0.f, 0.f, 0.f};
      tt = mfma16(pa0, ones, tt);
      tt = mfma16(pa1, ones, tt);
#pragma unroll
      for (int r = 0; r < 4; ++r) l[r] += tt[r];
    }

#pragma unroll
    for (int dt = 0; dt < 4; ++dt) {
      o[dt] = mfma16(pa0, va[dt * 2], o[dt]);
      o[dt] = mfma16(pa1, va[dt * 2 + 1], o[dt]);
    }
  }

  // ---- epilogue: write output fragment-packed (gemm2 A-operand) ----
  const int mi_g = b * 32 + (a16 >> 2);
#pragma unroll
  for (int dt = 0; dt < 4; ++dt)
#pragma unroll
    for (int r = 0; r < 4; ++r) {
      float val = o[dt][r] / l[r];
      __bf16 bx = (__bf16)val;
      int off16 = (((mi_g * 32 + h * 2 + (dt >> 1)) * 4 + (a16 & 3)) << 6) +
                  (((dt & 1) * 2 + (lr >> 3)) << 4) + lg * 4 + r;
      abp[(size_t)off16 * 8 + (lr & 7)] = *(u16*)&bx;
    }
}

extern "C" void kernel_launch(void* const* d_in, const int* in_sizes, int n_in,
                              void* d_out, int out_size, void* d_ws, size_t ws_size,
                              hipStream_t stream) {
  (void)in_sizes; (void)n_in; (void)out_size; (void)ws_size;
  const float* x = (const float*)d_in[0];
  const float* Wp = (const float*)d_in[1];
  const float* bp = (const float*)d_in[2];
  const float* Wo = (const float*)d_in[3];
  const float* bo = (const float*)d_in[4];
  float* out = (float*)d_out;

  char* ws = (char*)d_ws;
  u16* apx = (u16*)(ws);                        // 8 MB  x packed [64 mi]
  u16* bpx = (u16*)(ws + (size_t)(8u << 20));   // 6 MB  Wp packed [48 ni]
  u16* wox = (u16*)(ws + (size_t)(14u << 20));  // 2 MB  Wo packed [16 ni]
  u16* qbp = (u16*)(ws + (size_t)(16u << 20));  // 8 MB  Q row-major
  u16* kpp = (u16*)(ws + (size_t)(24u << 20));  // 8 MB  K fragment tiles
  u16* vpp = (u16*)(ws + (size_t)(32u << 20));  // 8 MB  V fragment tiles
  u16* abp = (u16*)(ws + (size_t)(40u << 20));  // 8 MB  attn out packed

  cvt3_kernel<<<2048, 256, 0, stream>>>(x, Wp, Wo, apx, bpx, wox);
  // gemm1: 16 mib x 48 nj = 768 four-wave blocks, XCD-local mi chunks
  gemm_frag<4, 1><<<768, 256, 0, stream>>>(
      apx, bpx, bp, nullptr, (__bf16*)qbp, (__bf16*)kpp, (__bf16*)vpp, 3072);
  attn_kernel<<<4096, 64, 0, stream>>>(
      (const __bf16*)qbp, (const __bf16*)kpp, (const __bf16*)vpp, abp);
  // gemm2: 16 mib x 32 nj(32-col) = 512 four-wave blocks -> 2 waves/SIMD
  gemm_frag<2, 0><<<512, 256, 0, stream>>>(
      abp, wox, bo, out, nullptr, nullptr, nullptr, 1024);
}